// Round 1
// baseline (489.040 us; speedup 1.0000x reference)
//
#include <hip/hip_runtime.h>

#define N_NODES 131072
#define BGRAPHS 512
#define FDIM    512
#define HDIM    256
#define NPG     256
#define KSEL    128
#define STAGES  16                 // K = 512 / 32
#define BSTAGE_SHORTS 24576        // 48 KB of B per stage (3 splits * 2 q * 8 nt * 64 lanes * 8 bf16)
#define A_ROW   40                 // A-plane row stride in shorts (32 + 8 pad, keeps 16B align)
#define A_PLANE (NPG * A_ROW)      // 10240 shorts per split plane

typedef __attribute__((ext_vector_type(8)))  short bf16x8;
typedef __attribute__((ext_vector_type(16))) float f32x16;

// RNE float -> bf16 (bit trick), also returns the bf16 value as float
__device__ __forceinline__ unsigned short bf16_rne(float f, float* back) {
    unsigned u = __float_as_uint(f);
    unsigned r = u + 0x7FFFu + ((u >> 16) & 1u);
    unsigned short h = (unsigned short)(r >> 16);
    *back = __uint_as_float(((unsigned)h) << 16);
    return h;
}

// ---------------------------------------------------------------------------
// K0: split W1 (fp32 [512][256]) into 3 bf16 planes in MFMA B-fragment order.
// uid = s*3072 + ((q*3 + p)*8 + nt)*64 + lane, 8 bf16 each,
// elem j = W1[s*32 + q*16 + (lane>>5)*8 + j][nt*32 + (lane&31)]  (split p).
// ---------------------------------------------------------------------------
__global__ __launch_bounds__(256)
void split_w1_kernel(const float* __restrict__ W1, unsigned short* __restrict__ wsB)
{
    const int uid  = blockIdx.x * 256 + threadIdx.x;     // 0..49151
    const int lane = uid & 63;
    int t = uid >> 6;
    const int nt = t & 7;  t >>= 3;
    const int p  = t % 3;  t /= 3;
    const int q  = t & 1;
    const int s  = t >> 1;
    const int n  = nt * 32 + (lane & 31);
    const int k0 = s * 32 + q * 16 + (lane >> 5) * 8;

    bf16x8 v;
    #pragma unroll
    for (int j = 0; j < 8; ++j) {
        float w = W1[(size_t)(k0 + j) * HDIM + n];
        float f1, f2, f3;
        unsigned short h1 = bf16_rne(w, &f1);
        float r1 = w - f1;
        unsigned short h2 = bf16_rne(r1, &f2);
        float r2 = r1 - f2;
        unsigned short h3 = bf16_rne(r2, &f3);
        v[j] = (short)(p == 0 ? h1 : (p == 1 ? h2 : h3));
    }
    *(bf16x8*)(wsB + (size_t)uid * 8) = v;
}

// ---------------------------------------------------------------------------
// K1 (FUSED, pipelined): one block per graph, 1024 threads = 16 waves.
// Wave grid 4x4: each wave owns a 64x64 output tile -> acc[2][2] = 64 regs,
// total ~115 regs/wave -> 4 waves/SIMD (vs. 2 before at acc[2][4]=128).
// Per-SIMD MFMA demand per stage unchanged; latency hiding doubled.
// LDS: B double-buffer 2x48KB + A-split 3 planes 60KB = 156KB (epilogue
// overlays B region after the K-loop). A prefetched to regs 1 stage ahead;
// split once per block into LDS; B staged async 1 stage ahead.
// ---------------------------------------------------------------------------
__global__ __launch_bounds__(1024)
void fused_kernel(const float* __restrict__ x,
                  const unsigned short* __restrict__ wsB,
                  const float* __restrict__ b1, const float* __restrict__ W2,
                  const float* __restrict__ b2,
                  float* __restrict__ pooled, float* __restrict__ mask_out,
                  float* __restrict__ loss_per_g)
{
    __shared__ __attribute__((aligned(16))) unsigned char smem[2 * 49152 + 3 * A_PLANE * 2];
    unsigned short* ldsA = (unsigned short*)(smem + 2 * 49152);

    const int g    = blockIdx.x;
    const int tid  = threadIdx.x;
    const int lane = tid & 63;
    const int wv   = tid >> 6;        // 0..15
    const int wy   = wv & 3;          // row quarter (64 rows)
    const int wx   = wv >> 2;         // col quarter (64 cols)
    const int l31  = lane & 31;
    const int lh   = lane >> 5;

    // A-staging ownership: thread owns row r, k-quarter qf (8 consecutive floats)
    const int r  = tid >> 2;
    const int qf = tid & 3;
    const float* aptr = x + ((size_t)(g * NPG + r)) * FDIM + qf * 8;

    f32x16 acc[2][2];
    #pragma unroll
    for (int a = 0; a < 2; ++a)
        #pragma unroll
        for (int b = 0; b < 2; ++b)
            #pragma unroll
            for (int rr = 0; rr < 16; ++rr) acc[a][b][rr] = 0.f;

    float4 pf0, pf1;

    // ---- prolog: stage 0
    pf0 = *(const float4*)(aptr + 0);
    pf1 = *(const float4*)(aptr + 4);
    {
        const unsigned short* src = wsB;            // stage 0
        #pragma unroll
        for (int i = 0; i < 3; ++i) {
            const int unit = i * 1024 + tid;
            __builtin_amdgcn_global_load_lds(
                (const __attribute__((address_space(1))) unsigned int*)(src + (size_t)unit * 8),
                (__attribute__((address_space(3))) unsigned int*)((unsigned short*)smem + unit * 8),
                16, 0, 0);
        }
    }
    // convert + write A(0) into LDS planes
    {
        float v[8] = {pf0.x, pf0.y, pf0.z, pf0.w, pf1.x, pf1.y, pf1.z, pf1.w};
        unsigned short H[8], M[8], L[8];
        #pragma unroll
        for (int j = 0; j < 8; ++j) {
            float f1, f2, f3;
            H[j] = bf16_rne(v[j], &f1);
            float r1 = v[j] - f1;
            M[j] = bf16_rne(r1, &f2);
            float r2 = r1 - f2;
            L[j] = bf16_rne(r2, &f3);
        }
        const int base = r * A_ROW + qf * 8;
        const unsigned short* P[3] = {H, M, L};
        #pragma unroll
        for (int p = 0; p < 3; ++p) {
            const unsigned short* s8 = P[p];
            uint4 u;
            u.x = (unsigned)s8[0] | ((unsigned)s8[1] << 16);
            u.y = (unsigned)s8[2] | ((unsigned)s8[3] << 16);
            u.z = (unsigned)s8[4] | ((unsigned)s8[5] << 16);
            u.w = (unsigned)s8[6] | ((unsigned)s8[7] << 16);
            *(uint4*)(ldsA + p * A_PLANE + base) = u;
        }
    }
    __syncthreads();

    // ---- main K loop
    for (int s = 0; s < STAGES; ++s) {
        if (s < STAGES - 1) {
            // B(s+1) async into the other buffer
            const unsigned short* src = wsB + (size_t)(s + 1) * BSTAGE_SHORTS;
            unsigned short* dstB = (unsigned short*)smem + ((s + 1) & 1) * BSTAGE_SHORTS;
            #pragma unroll
            for (int i = 0; i < 3; ++i) {
                const int unit = i * 1024 + tid;
                __builtin_amdgcn_global_load_lds(
                    (const __attribute__((address_space(1))) unsigned int*)(src + (size_t)unit * 8),
                    (__attribute__((address_space(3))) unsigned int*)(dstB + unit * 8),
                    16, 0, 0);
            }
            // A(s+1) prefetch into regs
            const float* ap = aptr + (s + 1) * 32;
            pf0 = *(const float4*)(ap + 0);
            pf1 = *(const float4*)(ap + 4);
        }

        // compute stage s
        const bf16x8* bfp = (const bf16x8*)((unsigned short*)smem + (s & 1) * BSTAGE_SHORTS);
        #pragma unroll
        for (int q = 0; q < 2; ++q) {
            const int a0off = (wy * 64 + l31) * A_ROW + q * 16 + lh * 8;
            const int a1off = a0off + 32 * A_ROW;
            bf16x8 A0h = *(const bf16x8*)(ldsA + 0 * A_PLANE + a0off);
            bf16x8 A0m = *(const bf16x8*)(ldsA + 1 * A_PLANE + a0off);
            bf16x8 A0l = *(const bf16x8*)(ldsA + 2 * A_PLANE + a0off);
            bf16x8 A1h = *(const bf16x8*)(ldsA + 0 * A_PLANE + a1off);
            bf16x8 A1m = *(const bf16x8*)(ldsA + 1 * A_PLANE + a1off);
            bf16x8 A1l = *(const bf16x8*)(ldsA + 2 * A_PLANE + a1off);
            const int nb = wx * 2;
            // Bh plane: HH, MH, LH products
            bf16x8 Bh0 = bfp[((q * 3 + 0) * 8 + nb + 0) * 64 + lane];
            bf16x8 Bh1 = bfp[((q * 3 + 0) * 8 + nb + 1) * 64 + lane];
            acc[0][0] = __builtin_amdgcn_mfma_f32_32x32x16_bf16(A0h, Bh0, acc[0][0], 0, 0, 0);
            acc[0][1] = __builtin_amdgcn_mfma_f32_32x32x16_bf16(A0h, Bh1, acc[0][1], 0, 0, 0);
            acc[1][0] = __builtin_amdgcn_mfma_f32_32x32x16_bf16(A1h, Bh0, acc[1][0], 0, 0, 0);
            acc[1][1] = __builtin_amdgcn_mfma_f32_32x32x16_bf16(A1h, Bh1, acc[1][1], 0, 0, 0);
            acc[0][0] = __builtin_amdgcn_mfma_f32_32x32x16_bf16(A0m, Bh0, acc[0][0], 0, 0, 0);
            acc[0][1] = __builtin_amdgcn_mfma_f32_32x32x16_bf16(A0m, Bh1, acc[0][1], 0, 0, 0);
            acc[1][0] = __builtin_amdgcn_mfma_f32_32x32x16_bf16(A1m, Bh0, acc[1][0], 0, 0, 0);
            acc[1][1] = __builtin_amdgcn_mfma_f32_32x32x16_bf16(A1m, Bh1, acc[1][1], 0, 0, 0);
            acc[0][0] = __builtin_amdgcn_mfma_f32_32x32x16_bf16(A0l, Bh0, acc[0][0], 0, 0, 0);
            acc[0][1] = __builtin_amdgcn_mfma_f32_32x32x16_bf16(A0l, Bh1, acc[0][1], 0, 0, 0);
            acc[1][0] = __builtin_amdgcn_mfma_f32_32x32x16_bf16(A1l, Bh0, acc[1][0], 0, 0, 0);
            acc[1][1] = __builtin_amdgcn_mfma_f32_32x32x16_bf16(A1l, Bh1, acc[1][1], 0, 0, 0);
            // Bm plane: HM, MM products
            bf16x8 Bm0 = bfp[((q * 3 + 1) * 8 + nb + 0) * 64 + lane];
            bf16x8 Bm1 = bfp[((q * 3 + 1) * 8 + nb + 1) * 64 + lane];
            acc[0][0] = __builtin_amdgcn_mfma_f32_32x32x16_bf16(A0h, Bm0, acc[0][0], 0, 0, 0);
            acc[0][1] = __builtin_amdgcn_mfma_f32_32x32x16_bf16(A0h, Bm1, acc[0][1], 0, 0, 0);
            acc[1][0] = __builtin_amdgcn_mfma_f32_32x32x16_bf16(A1h, Bm0, acc[1][0], 0, 0, 0);
            acc[1][1] = __builtin_amdgcn_mfma_f32_32x32x16_bf16(A1h, Bm1, acc[1][1], 0, 0, 0);
            acc[0][0] = __builtin_amdgcn_mfma_f32_32x32x16_bf16(A0m, Bm0, acc[0][0], 0, 0, 0);
            acc[0][1] = __builtin_amdgcn_mfma_f32_32x32x16_bf16(A0m, Bm1, acc[0][1], 0, 0, 0);
            acc[1][0] = __builtin_amdgcn_mfma_f32_32x32x16_bf16(A1m, Bm0, acc[1][0], 0, 0, 0);
            acc[1][1] = __builtin_amdgcn_mfma_f32_32x32x16_bf16(A1m, Bm1, acc[1][1], 0, 0, 0);
            // Bl plane: HL product
            bf16x8 Bl0 = bfp[((q * 3 + 2) * 8 + nb + 0) * 64 + lane];
            bf16x8 Bl1 = bfp[((q * 3 + 2) * 8 + nb + 1) * 64 + lane];
            acc[0][0] = __builtin_amdgcn_mfma_f32_32x32x16_bf16(A0h, Bl0, acc[0][0], 0, 0, 0);
            acc[0][1] = __builtin_amdgcn_mfma_f32_32x32x16_bf16(A0h, Bl1, acc[0][1], 0, 0, 0);
            acc[1][0] = __builtin_amdgcn_mfma_f32_32x32x16_bf16(A1h, Bl0, acc[1][0], 0, 0, 0);
            acc[1][1] = __builtin_amdgcn_mfma_f32_32x32x16_bf16(A1h, Bl1, acc[1][1], 0, 0, 0);
        }
        __syncthreads();   // drains vmcnt: B(s+1) + A(s+1) landed; all waves done with ldsA(s)/B(s)

        if (s < STAGES - 1) {
            float v[8] = {pf0.x, pf0.y, pf0.z, pf0.w, pf1.x, pf1.y, pf1.z, pf1.w};
            unsigned short H[8], M[8], L[8];
            #pragma unroll
            for (int j = 0; j < 8; ++j) {
                float f1, f2, f3;
                H[j] = bf16_rne(v[j], &f1);
                float r1 = v[j] - f1;
                M[j] = bf16_rne(r1, &f2);
                float r2 = r1 - f2;
                L[j] = bf16_rne(r2, &f3);
            }
            const int base = r * A_ROW + qf * 8;
            const unsigned short* P[3] = {H, M, L};
            #pragma unroll
            for (int p = 0; p < 3; ++p) {
                const unsigned short* s8 = P[p];
                uint4 u;
                u.x = (unsigned)s8[0] | ((unsigned)s8[1] << 16);
                u.y = (unsigned)s8[2] | ((unsigned)s8[3] << 16);
                u.z = (unsigned)s8[4] | ((unsigned)s8[5] << 16);
                u.w = (unsigned)s8[6] | ((unsigned)s8[7] << 16);
                *(uint4*)(ldsA + p * A_PLANE + base) = u;
            }
        }
        __syncthreads();   // ldsA(s+1) visible before next compute
    }

    // ---- epilogue (overlays the B-buffer region of smem)
    float* Sp   = (float*)smem;            // [4][256] partial scores per col-quarter
    float* sv   = Sp + 4 * NPG;            // [256]
    int*   selr = (int*)(sv + NPG);        // [128]
    float* redT = (float*)(selr + KSEL);   // [256]
    float* redS = redT + NPG;              // [256]
    float* gprt = redS + NPG;              // [512]

    float bb[2], ww[2];
    #pragma unroll
    for (int nt = 0; nt < 2; ++nt) {
        const int c = wx * 64 + nt * 32 + l31;
        bb[nt] = b1[c];
        ww[nt] = W2[c];
    }
    #pragma unroll
    for (int mt = 0; mt < 2; ++mt) {
        float pr[16];
        #pragma unroll
        for (int rr = 0; rr < 16; ++rr) pr[rr] = 0.f;
        #pragma unroll
        for (int nt = 0; nt < 2; ++nt)
            #pragma unroll
            for (int rr = 0; rr < 16; ++rr) {
                float h = acc[mt][nt][rr] + bb[nt];
                h = h > 0.f ? h : 0.f;
                pr[rr] = fmaf(h, ww[nt], pr[rr]);
            }
        #pragma unroll
        for (int mask = 1; mask <= 16; mask <<= 1)
            #pragma unroll
            for (int rr = 0; rr < 16; ++rr)
                pr[rr] += __shfl_xor(pr[rr], mask);
        if (l31 == 0) {
            #pragma unroll
            for (int rr = 0; rr < 16; ++rr) {
                const int row = wy * 64 + mt * 32 + (rr & 3) + 8 * (rr >> 2) + 4 * lh;
                Sp[wx * NPG + row] = pr[rr];
            }
        }
    }
    __syncthreads();

    float sc = 0.f;
    if (tid < NPG) {
        sc = b2[0] + Sp[tid] + Sp[NPG + tid] + Sp[2 * NPG + tid] + Sp[3 * NPG + tid];
        sv[tid] = sc;
    }
    __syncthreads();

    // selection: exact rank (score desc, index asc on ties)
    if (tid < NPG) {
        int rank = 0;
        for (int j = 0; j < NPG; ++j) {
            const float sj = sv[j];
            rank += (sj > sc || (sj == sc && j < tid)) ? 1 : 0;
        }
        const bool sel = rank < KSEL;
        mask_out[g * NPG + tid] = sel ? 1.0f : 0.0f;
        if (sel) selr[rank] = tid;
        redT[tid] = sc;
        redS[tid] = sel ? sc : 0.f;
    }
    __syncthreads();

    for (int off = 128; off > 0; off >>= 1) {
        if (tid < off) { redT[tid] += redT[tid + off]; redS[tid] += redS[tid + off]; }
        __syncthreads();
    }
    if (tid == 0) {
        const float tot = redT[0], ssum = redS[0];
        const float sel_mean = ssum * (1.0f / KSEL);
        const float uns_mean = (tot - ssum) * (1.0f / (NPG - KSEL));
        const float v = 0.5f - (sel_mean - uns_mean);
        loss_per_g[g] = v > 0.f ? v : 0.f;
    }

    // pooled gather; 2 threads per col (64 selected rows each), rows L2/L3-warm
    const int col = tid & 511;
    const int h2  = tid >> 9;
    const float* __restrict__ xg = x + (size_t)g * NPG * FDIM;
    float a0 = 0.f, a1 = 0.f, a2 = 0.f, a3 = 0.f;
    #pragma unroll 4
    for (int n = 0; n < 64; n += 4) {
        const int base = h2 * 64 + n;
        a0 += xg[(size_t)selr[base + 0] * FDIM + col];
        a1 += xg[(size_t)selr[base + 1] * FDIM + col];
        a2 += xg[(size_t)selr[base + 2] * FDIM + col];
        a3 += xg[(size_t)selr[base + 3] * FDIM + col];
    }
    const float part = (a0 + a1) + (a2 + a3);
    if (h2) gprt[col] = part;
    __syncthreads();
    if (!h2) pooled[g * FDIM + col] = part + gprt[col];
}

// ---------------------------------------------------------------------------
// K2: topk_loss = sum(loss_per_g) / B * 0.2
// ---------------------------------------------------------------------------
__global__ __launch_bounds__(256)
void loss_kernel(const float* __restrict__ loss_per_g, float* __restrict__ out_loss)
{
    __shared__ float red[256];
    const int t = threadIdx.x;
    red[t] = loss_per_g[t] + loss_per_g[t + 256];
    __syncthreads();
    for (int off = 128; off > 0; off >>= 1) {
        if (t < off) red[t] += red[t + off];
        __syncthreads();
    }
    if (t == 0) out_loss[0] = red[0] * (0.2f / BGRAPHS);
}

extern "C" void kernel_launch(void* const* d_in, const int* in_sizes, int n_in,
                              void* d_out, int out_size, void* d_ws, size_t ws_size,
                              hipStream_t stream)
{
    const float* x  = (const float*)d_in[0];
    const float* W1 = (const float*)d_in[2];
    const float* b1 = (const float*)d_in[3];
    const float* W2 = (const float*)d_in[4];
    const float* b2 = (const float*)d_in[5];

    float* out    = (float*)d_out;
    float* pooled = out;                       // [512*512]
    float* loss   = out + BGRAPHS * FDIM;      // [1]
    float* mask   = loss + 1;                  // [131072]

    float* loss_g       = (float*)d_ws;                               // 2 KB
    unsigned short* wsB = (unsigned short*)((char*)d_ws + 4096);      // 768 KB

    split_w1_kernel<<<192, 256, 0, stream>>>(W1, wsB);
    fused_kernel<<<BGRAPHS, 1024, 0, stream>>>(x, wsB, b1, W2, b2,
                                               pooled, mask, loss_g);
    loss_kernel<<<1, 256, 0, stream>>>(loss_g, loss);
}

// Round 2
// 434.288 us; speedup vs baseline: 1.1261x; 1.1261x over previous
//
#include <hip/hip_runtime.h>

#define BGRAPHS 512
#define FDIM    512
#define HDIM    256
#define NPG     256
#define KSEL    128
#define STAGES  16                 // K = 512 / 32
#define BSTAGE_SHORTS 16384        // 32 KB per stage: 2 planes * 2 q * 8 nt * 64 lanes * 8 f16
#define A_ROW   40                 // A-plane row stride in shorts (32 + 8 pad, 16B aligned rows)
#define A_PLANE (NPG * A_ROW)      // 10240 shorts per plane
// LDS map: B dbuf 2*32768 B = 65536; A dbuf 2 bufs * 2 planes * 20480 B = 81920; total 147456

typedef __attribute__((ext_vector_type(8)))  _Float16 f16x8;
typedef __attribute__((ext_vector_type(8)))  short    s16x8;
typedef __attribute__((ext_vector_type(16))) float    f32x16;

// RNE float -> fp16 bits, also returns the fp16 value back as float
__device__ __forceinline__ unsigned short f16_rne(float f, float* back) {
    _Float16 h = (_Float16)f;          // v_cvt_f16_f32, RNE
    *back = (float)h;
    union { _Float16 h; unsigned short s; } cv; cv.h = h;
    return cv.s;
}

// ---------------------------------------------------------------------------
// K0: split W1 (fp32 [512][256], pre-scaled x1024) into 2 fp16 planes in MFMA
// B-fragment order. uid = s*2048 + ((q*2 + p)*8 + nt)*64 + lane, 8 f16 each,
// elem j = W1[s*32 + q*16 + (lane>>5)*8 + j][nt*32 + (lane&31)]  (plane p).
// ---------------------------------------------------------------------------
__global__ __launch_bounds__(256)
void split_w1_kernel(const float* __restrict__ W1, unsigned short* __restrict__ wsB)
{
    const int uid  = blockIdx.x * 256 + threadIdx.x;     // 0..32767
    const int lane = uid & 63;
    int t = uid >> 6;
    const int nt = t & 7;  t >>= 3;
    const int p  = t & 1;  t >>= 1;
    const int q  = t & 1;
    const int s  = t >> 1;
    const int n  = nt * 32 + (lane & 31);
    const int k0 = s * 32 + q * 16 + (lane >> 5) * 8;

    s16x8 v;
    #pragma unroll
    for (int j = 0; j < 8; ++j) {
        float w = W1[(size_t)(k0 + j) * HDIM + n] * 1024.0f;   // B scale 2^10
        float f1, f2;
        unsigned short h1 = f16_rne(w, &f1);
        unsigned short h2 = f16_rne(w - f1, &f2);
        v[j] = (short)(p ? h2 : h1);
    }
    *(s16x8*)(wsB + (size_t)uid * 8) = v;
}

// ---------------------------------------------------------------------------
// K1 (FUSED): one block per graph, 512 threads = 8 waves (4 wy x 2 wx),
// wave tile 64x128, acc[2][4]. fp16 2-plane, 4 products (HH,MH,HM,MM),
// A x2^6, B x2^10, unscale 2^-16 at epilogue.
// Double-buffered B (global_load_lds) AND double-buffered A planes ->
// ONE barrier per stage: convert(s+1) writes the other A buffer while
// compute(s) runs; single __syncthreads drains gll + makes writes visible.
// ---------------------------------------------------------------------------
__global__ __launch_bounds__(512, 2)
void fused_kernel(const float* __restrict__ x,
                  const unsigned short* __restrict__ wsB,
                  const float* __restrict__ b1, const float* __restrict__ W2,
                  const float* __restrict__ b2,
                  float* __restrict__ pooled, float* __restrict__ mask_out,
                  float* __restrict__ loss_per_g)
{
    __shared__ __attribute__((aligned(16))) unsigned char smem[147456];

    const int g    = blockIdx.x;
    const int tid  = threadIdx.x;
    const int lane = tid & 63;
    const int wv   = tid >> 6;        // 0..7
    const int wy   = wv & 3;          // row quarter (64 rows)
    const int wx   = wv >> 2;         // col half (128 cols)
    const int l31  = lane & 31;
    const int lh   = lane >> 5;

    // A-staging ownership: thread owns row r, k-half hf (16 consecutive floats)
    const int r  = tid >> 1;
    const int hf = tid & 1;
    const float* aptr = x + ((size_t)(g * NPG + r)) * FDIM + hf * 16;

    f32x16 acc[2][4];
    #pragma unroll
    for (int a = 0; a < 2; ++a)
        #pragma unroll
        for (int b = 0; b < 4; ++b)
            #pragma unroll
            for (int rr = 0; rr < 16; ++rr) acc[a][b][rr] = 0.f;

    float4 aA0, aA1, aA2, aA3;   // prefetch set A
    float4 aB0, aB1, aB2, aB3;   // prefetch set B

#define GLL_B(S1) do {                                                          \
    const unsigned short* _src = wsB + (size_t)(S1) * BSTAGE_SHORTS;            \
    unsigned short* _dst = (unsigned short*)smem + ((S1) & 1) * BSTAGE_SHORTS;  \
    _Pragma("unroll")                                                           \
    for (int _i = 0; _i < 4; ++_i) {                                            \
        const int _u = _i * 512 + tid;                                          \
        __builtin_amdgcn_global_load_lds(                                       \
            (const __attribute__((address_space(1))) unsigned int*)(_src + (size_t)_u * 8), \
            (__attribute__((address_space(3))) unsigned int*)(_dst + _u * 8),   \
            16, 0, 0);                                                          \
    } } while (0)

#define LOAD_PF(P0,P1,P2,P3,S2) do {                                            \
    const float* _ap = aptr + (S2) * 32;                                        \
    P0 = *(const float4*)(_ap + 0);  P1 = *(const float4*)(_ap + 4);            \
    P2 = *(const float4*)(_ap + 8);  P3 = *(const float4*)(_ap + 12); } while (0)

#define CONVERT_A(P0,P1,P2,P3,BUF) do {                                         \
    float _v[16] = {P0.x,P0.y,P0.z,P0.w,P1.x,P1.y,P1.z,P1.w,                    \
                    P2.x,P2.y,P2.z,P2.w,P3.x,P3.y,P3.z,P3.w};                   \
    unsigned short _H[16], _M[16];                                              \
    _Pragma("unroll")                                                           \
    for (int _j = 0; _j < 16; ++_j) {                                           \
        float _f1, _f2;                                                         \
        float _xs = _v[_j] * 64.0f;      /* A scale 2^6 */                      \
        _H[_j] = f16_rne(_xs, &_f1);                                            \
        _M[_j] = f16_rne(_xs - _f1, &_f2);                                      \
        (void)_f2;                                                              \
    }                                                                           \
    unsigned short* _pl = (unsigned short*)(smem + 65536 + (BUF) * 40960)       \
                          + r * A_ROW + hf * 16;                                \
    uint4 _u0, _u1;                                                             \
    _u0.x = (unsigned)_H[0]  | ((unsigned)_H[1]  << 16);                        \
    _u0.y = (unsigned)_H[2]  | ((unsigned)_H[3]  << 16);                        \
    _u0.z = (unsigned)_H[4]  | ((unsigned)_H[5]  << 16);                        \
    _u0.w = (unsigned)_H[6]  | ((unsigned)_H[7]  << 16);                        \
    _u1.x = (unsigned)_H[8]  | ((unsigned)_H[9]  << 16);                        \
    _u1.y = (unsigned)_H[10] | ((unsigned)_H[11] << 16);                        \
    _u1.z = (unsigned)_H[12] | ((unsigned)_H[13] << 16);                        \
    _u1.w = (unsigned)_H[14] | ((unsigned)_H[15] << 16);                        \
    ((uint4*)_pl)[0] = _u0; ((uint4*)_pl)[1] = _u1;                             \
    _u0.x = (unsigned)_M[0]  | ((unsigned)_M[1]  << 16);                        \
    _u0.y = (unsigned)_M[2]  | ((unsigned)_M[3]  << 16);                        \
    _u0.z = (unsigned)_M[4]  | ((unsigned)_M[5]  << 16);                        \
    _u0.w = (unsigned)_M[6]  | ((unsigned)_M[7]  << 16);                        \
    _u1.x = (unsigned)_M[8]  | ((unsigned)_M[9]  << 16);                        \
    _u1.y = (unsigned)_M[10] | ((unsigned)_M[11] << 16);                        \
    _u1.z = (unsigned)_M[12] | ((unsigned)_M[13] << 16);                        \
    _u1.w = (unsigned)_M[14] | ((unsigned)_M[15] << 16);                        \
    ((uint4*)(_pl + A_PLANE))[0] = _u0; ((uint4*)(_pl + A_PLANE))[1] = _u1;     \
    } while (0)

#define COMPUTE(BUF) do {                                                       \
    const f16x8* _bfp = (const f16x8*)(smem + (BUF) * (BSTAGE_SHORTS * 2));     \
    const unsigned short* _aB = (const unsigned short*)(smem + 65536 + (BUF) * 40960); \
    _Pragma("unroll")                                                           \
    for (int _q = 0; _q < 2; ++_q) {                                            \
        const int _a0 = (wy * 64 + l31) * A_ROW + _q * 16 + lh * 8;             \
        const int _a1 = _a0 + 32 * A_ROW;                                       \
        f16x8 A0h = *(const f16x8*)(_aB + _a0);                                 \
        f16x8 A0m = *(const f16x8*)(_aB + A_PLANE + _a0);                       \
        f16x8 A1h = *(const f16x8*)(_aB + _a1);                                 \
        f16x8 A1m = *(const f16x8*)(_aB + A_PLANE + _a1);                       \
        _Pragma("unroll")                                                       \
        for (int _nt = 0; _nt < 4; ++_nt) {                                     \
            const int _nn = wx * 4 + _nt;                                       \
            f16x8 Bh = _bfp[((_q * 2 + 0) * 8 + _nn) * 64 + lane];              \
            f16x8 Bm = _bfp[((_q * 2 + 1) * 8 + _nn) * 64 + lane];              \
            acc[0][_nt] = __builtin_amdgcn_mfma_f32_32x32x16_f16(A0h, Bh, acc[0][_nt], 0, 0, 0); \
            acc[1][_nt] = __builtin_amdgcn_mfma_f32_32x32x16_f16(A1h, Bh, acc[1][_nt], 0, 0, 0); \
            acc[0][_nt] = __builtin_amdgcn_mfma_f32_32x32x16_f16(A0m, Bh, acc[0][_nt], 0, 0, 0); \
            acc[1][_nt] = __builtin_amdgcn_mfma_f32_32x32x16_f16(A1m, Bh, acc[1][_nt], 0, 0, 0); \
            acc[0][_nt] = __builtin_amdgcn_mfma_f32_32x32x16_f16(A0h, Bm, acc[0][_nt], 0, 0, 0); \
            acc[1][_nt] = __builtin_amdgcn_mfma_f32_32x32x16_f16(A1h, Bm, acc[1][_nt], 0, 0, 0); \
            acc[0][_nt] = __builtin_amdgcn_mfma_f32_32x32x16_f16(A0m, Bm, acc[0][_nt], 0, 0, 0); \
            acc[1][_nt] = __builtin_amdgcn_mfma_f32_32x32x16_f16(A1m, Bm, acc[1][_nt], 0, 0, 0); \
        }                                                                       \
    } } while (0)

    // ---- prolog: stage 0 in buffers 0, prefetch x(1)
    LOAD_PF(aA0, aA1, aA2, aA3, 0);
    GLL_B(0);
    CONVERT_A(aA0, aA1, aA2, aA3, 0);
    LOAD_PF(aA0, aA1, aA2, aA3, 1);
    __syncthreads();

    // ---- main K loop: 2 stages per iteration (register-set alternation)
    for (int s = 0; s < STAGES; s += 2) {
        // even stage s (buffers 0): convert aA -> buf1, load aB <- x(s+2)
        if (s < STAGES - 1) GLL_B(s + 1);
        if (s < STAGES - 2) LOAD_PF(aB0, aB1, aB2, aB3, s + 2);
        COMPUTE(0);
        if (s < STAGES - 1) CONVERT_A(aA0, aA1, aA2, aA3, 1);
        __syncthreads();

        // odd stage s+1 (buffers 1): convert aB -> buf0, load aA <- x(s+3)
        if (s + 1 < STAGES - 1) GLL_B(s + 2);
        if (s + 1 < STAGES - 2) LOAD_PF(aA0, aA1, aA2, aA3, s + 3);
        COMPUTE(1);
        if (s + 1 < STAGES - 1) CONVERT_A(aB0, aB1, aB2, aB3, 0);
        __syncthreads();
    }

    // ---- epilogue (overlays the B-buffer region of smem)
    float* Sp   = (float*)smem;            // [2][256]
    float* sv   = Sp + 2 * NPG;            // [256]
    int*   selr = (int*)(sv + NPG);        // [128]
    float* redT = (float*)(selr + KSEL);   // [256]
    float* redS = redT + NPG;              // [256]

    float bb[4], ww[4];
    #pragma unroll
    for (int nt = 0; nt < 4; ++nt) {
        const int c = wx * 128 + nt * 32 + l31;
        bb[nt] = b1[c];
        ww[nt] = W2[c];
    }
    const float unscale = 1.0f / 65536.0f;   // 2^-(6+10)
    #pragma unroll
    for (int mt = 0; mt < 2; ++mt) {
        float pr[16];
        #pragma unroll
        for (int rr = 0; rr < 16; ++rr) pr[rr] = 0.f;
        #pragma unroll
        for (int nt = 0; nt < 4; ++nt)
            #pragma unroll
            for (int rr = 0; rr < 16; ++rr) {
                float h = fmaf(acc[mt][nt][rr], unscale, bb[nt]);
                h = h > 0.f ? h : 0.f;
                pr[rr] = fmaf(h, ww[nt], pr[rr]);
            }
        #pragma unroll
        for (int mask = 1; mask <= 16; mask <<= 1)
            #pragma unroll
            for (int rr = 0; rr < 16; ++rr)
                pr[rr] += __shfl_xor(pr[rr], mask);
        if (l31 == 0) {
            #pragma unroll
            for (int rr = 0; rr < 16; ++rr) {
                const int row = wy * 64 + mt * 32 + (rr & 3) + 8 * (rr >> 2) + 4 * lh;
                Sp[wx * NPG + row] = pr[rr];
            }
        }
    }
    __syncthreads();

    float sc = 0.f;
    if (tid < NPG) {
        sc = b2[0] + Sp[tid] + Sp[NPG + tid];
        sv[tid] = sc;
    }
    __syncthreads();

    // selection: exact rank (score desc, index asc on ties)
    if (tid < NPG) {
        int rank = 0;
        for (int j = 0; j < NPG; ++j) {
            const float sj = sv[j];
            rank += (sj > sc || (sj == sc && j < tid)) ? 1 : 0;
        }
        const bool sel = rank < KSEL;
        mask_out[g * NPG + tid] = sel ? 1.0f : 0.0f;
        if (sel) selr[rank] = tid;
        redT[tid] = sc;
        redS[tid] = sel ? sc : 0.f;
    }
    __syncthreads();

    for (int off = 128; off > 0; off >>= 1) {
        if (tid < off) { redT[tid] += redT[tid + off]; redS[tid] += redS[tid + off]; }
        __syncthreads();
    }
    if (tid == 0) {
        const float tot = redT[0], ssum = redS[0];
        const float sel_mean = ssum * (1.0f / KSEL);
        const float uns_mean = (tot - ssum) * (1.0f / (NPG - KSEL));
        const float v = 0.5f - (sel_mean - uns_mean);
        loss_per_g[g] = v > 0.f ? v : 0.f;
    }

    // pooled gather; col per thread, rows L2/L3-warm
    const int col = tid;
    const float* __restrict__ xg = x + (size_t)g * NPG * FDIM;
    float a0 = 0.f, a1 = 0.f, a2 = 0.f, a3 = 0.f;
    #pragma unroll 4
    for (int n = 0; n < KSEL; n += 4) {
        a0 += xg[(size_t)selr[n + 0] * FDIM + col];
        a1 += xg[(size_t)selr[n + 1] * FDIM + col];
        a2 += xg[(size_t)selr[n + 2] * FDIM + col];
        a3 += xg[(size_t)selr[n + 3] * FDIM + col];
    }
    pooled[g * FDIM + col] = (a0 + a1) + (a2 + a3);

#undef GLL_B
#undef LOAD_PF
#undef CONVERT_A
#undef COMPUTE
}

// ---------------------------------------------------------------------------
// K2: topk_loss = sum(loss_per_g) / B * 0.2
// ---------------------------------------------------------------------------
__global__ __launch_bounds__(256)
void loss_kernel(const float* __restrict__ loss_per_g, float* __restrict__ out_loss)
{
    __shared__ float red[256];
    const int t = threadIdx.x;
    red[t] = loss_per_g[t] + loss_per_g[t + 256];
    __syncthreads();
    for (int off = 128; off > 0; off >>= 1) {
        if (t < off) red[t] += red[t + off];
        __syncthreads();
    }
    if (t == 0) out_loss[0] = red[0] * (0.2f / BGRAPHS);
}

extern "C" void kernel_launch(void* const* d_in, const int* in_sizes, int n_in,
                              void* d_out, int out_size, void* d_ws, size_t ws_size,
                              hipStream_t stream)
{
    const float* x  = (const float*)d_in[0];
    const float* W1 = (const float*)d_in[2];
    const float* b1 = (const float*)d_in[3];
    const float* W2 = (const float*)d_in[4];
    const float* b2 = (const float*)d_in[5];

    float* out    = (float*)d_out;
    float* pooled = out;                       // [512*512]
    float* loss   = out + BGRAPHS * FDIM;      // [1]
    float* mask   = loss + 1;                  // [131072]

    float* loss_g       = (float*)d_ws;                               // 2 KB
    unsigned short* wsB = (unsigned short*)((char*)d_ws + 4096);      // 512 KB

    split_w1_kernel<<<128, 256, 0, stream>>>(W1, wsB);
    fused_kernel<<<BGRAPHS, 512, 0, stream>>>(x, wsB, b1, W2, b2,
                                              pooled, mask, loss_g);
    loss_kernel<<<1, 256, 0, stream>>>(loss_g, loss);
}

// Round 3
// 417.303 us; speedup vs baseline: 1.1719x; 1.0407x over previous
//
#include <hip/hip_runtime.h>

#define BGRAPHS 512
#define FDIM    512
#define HDIM    256
#define NPG     256
#define KSEL    128
#define STAGES  16                 // K = 512 / 32
#define BSTAGE_SHORTS 16384        // 32 KB per stage: 2 planes * 2 q * 8 nt * 64 lanes * 8 f16
#define A_ROW   40                 // A-plane row stride in shorts (32 + 8 pad, 16B aligned rows)
#define A_PLANE (NPG * A_ROW)      // 10240 shorts per plane
// LDS map: B dbuf 2*32768 B = 65536; A dbuf 2 bufs * 2 planes * 20480 B = 81920; total 147456

typedef __attribute__((ext_vector_type(8)))  _Float16 f16x8;
typedef __attribute__((ext_vector_type(8)))  short    s16x8;
typedef __attribute__((ext_vector_type(16))) float    f32x16;

// RNE float -> fp16 bits, also returns the fp16 value back as float
__device__ __forceinline__ unsigned short f16_rne(float f, float* back) {
    _Float16 h = (_Float16)f;          // v_cvt_f16_f32, RNE
    *back = (float)h;
    union { _Float16 h; unsigned short s; } cv; cv.h = h;
    return cv.s;
}

// ---------------------------------------------------------------------------
// K0: split W1 (fp32 [512][256], pre-scaled x1024) into 2 fp16 planes in MFMA
// B-fragment order. uid = s*2048 + ((q*2 + p)*8 + nt)*64 + lane, 8 f16 each,
// elem j = W1[s*32 + q*16 + (lane>>5)*8 + j][nt*32 + (lane&31)]  (plane p).
// ---------------------------------------------------------------------------
__global__ __launch_bounds__(256)
void split_w1_kernel(const float* __restrict__ W1, unsigned short* __restrict__ wsB)
{
    const int uid  = blockIdx.x * 256 + threadIdx.x;     // 0..32767
    const int lane = uid & 63;
    int t = uid >> 6;
    const int nt = t & 7;  t >>= 3;
    const int p  = t & 1;  t >>= 1;
    const int q  = t & 1;
    const int s  = t >> 1;
    const int n  = nt * 32 + (lane & 31);
    const int k0 = s * 32 + q * 16 + (lane >> 5) * 8;

    s16x8 v;
    #pragma unroll
    for (int j = 0; j < 8; ++j) {
        float w = W1[(size_t)(k0 + j) * HDIM + n] * 1024.0f;   // B scale 2^10
        float f1, f2;
        unsigned short h1 = f16_rne(w, &f1);
        unsigned short h2 = f16_rne(w - f1, &f2);
        v[j] = (short)(p ? h2 : h1);
    }
    *(s16x8*)(wsB + (size_t)uid * 8) = v;
}

// ---------------------------------------------------------------------------
// K1 (FUSED): one block per graph, 512 threads = 8 waves (4 wy x 2 wx),
// wave tile 64x128, acc[2][4]. fp16 2-plane, 3 products (HH, MH, HM; MM
// dropped: |Am*Bm| <= 2^-22 rel -> ~3e-7 on scores). A x2^6, B x2^10,
// unscale 2^-16 at epilogue.
// x staging COALESCED: thread t owns 16B chunk (t&7) of rows (t>>3)+{0,64,
// 128,192}; each load instr covers 8 rows x 128 B contiguous -> 16 full
// 64B lines (vs 64 quarter-used lines in the row-per-lane-pair mapping).
// Double-buffered B (global_load_lds) AND double-buffered A planes ->
// ONE barrier per stage.
// ---------------------------------------------------------------------------
__global__ __launch_bounds__(512, 2)
void fused_kernel(const float* __restrict__ x,
                  const unsigned short* __restrict__ wsB,
                  const float* __restrict__ b1, const float* __restrict__ W2,
                  const float* __restrict__ b2,
                  float* __restrict__ pooled, float* __restrict__ mask_out,
                  float* __restrict__ loss_per_g)
{
    __shared__ __attribute__((aligned(16))) unsigned char smem[147456];

    const int g    = blockIdx.x;
    const int tid  = threadIdx.x;
    const int lane = tid & 63;
    const int wv   = tid >> 6;        // 0..7
    const int wy   = wv & 3;          // row quarter (64 rows)
    const int wx   = wv >> 2;         // col half (128 cols)
    const int l31  = lane & 31;
    const int lh   = lane >> 5;

    // A-staging ownership: thread owns chunk c (16B) of rows rbase + 64k
    const int c     = tid & 7;
    const int rbase = tid >> 3;       // 0..63
    const float* aptr = x + ((size_t)(g * NPG + rbase)) * FDIM + c * 4;

    f32x16 acc[2][4];
    #pragma unroll
    for (int a = 0; a < 2; ++a)
        #pragma unroll
        for (int b = 0; b < 4; ++b)
            #pragma unroll
            for (int rr = 0; rr < 16; ++rr) acc[a][b][rr] = 0.f;

    float4 aA0, aA1, aA2, aA3;   // prefetch set A (k = 0..3)
    float4 aB0, aB1, aB2, aB3;   // prefetch set B

#define GLL_B(S1) do {                                                          \
    const unsigned short* _src = wsB + (size_t)(S1) * BSTAGE_SHORTS;            \
    unsigned short* _dst = (unsigned short*)smem + ((S1) & 1) * BSTAGE_SHORTS;  \
    _Pragma("unroll")                                                           \
    for (int _i = 0; _i < 4; ++_i) {                                            \
        const int _u = _i * 512 + tid;                                          \
        __builtin_amdgcn_global_load_lds(                                       \
            (const __attribute__((address_space(1))) unsigned int*)(_src + (size_t)_u * 8), \
            (__attribute__((address_space(3))) unsigned int*)(_dst + _u * 8),   \
            16, 0, 0);                                                          \
    } } while (0)

#define LOAD_PF(P0,P1,P2,P3,S2) do {                                            \
    const float* _ap = aptr + (S2) * 32;                                        \
    P0 = *(const float4*)(_ap + 0 * 64 * FDIM);                                 \
    P1 = *(const float4*)(_ap + 1 * 64 * FDIM);                                 \
    P2 = *(const float4*)(_ap + 2 * 64 * FDIM);                                 \
    P3 = *(const float4*)(_ap + 3 * 64 * FDIM); } while (0)

#define CONV1(P,KK,BUF) do {                                                    \
    float _f[4] = {P.x, P.y, P.z, P.w};                                         \
    unsigned short _H[4], _M[4];                                                \
    _Pragma("unroll")                                                           \
    for (int _j = 0; _j < 4; ++_j) {                                            \
        float _b1v, _b2v;                                                       \
        float _xs = _f[_j] * 64.0f;      /* A scale 2^6 */                      \
        _H[_j] = f16_rne(_xs, &_b1v);                                           \
        _M[_j] = f16_rne(_xs - _b1v, &_b2v);                                    \
        (void)_b2v;                                                             \
    }                                                                           \
    unsigned short* _pl = (unsigned short*)(smem + 65536 + (BUF) * 40960)       \
                          + (rbase + 64 * (KK)) * A_ROW + c * 4;                \
    uint2 _uH, _uM;                                                             \
    _uH.x = (unsigned)_H[0] | ((unsigned)_H[1] << 16);                          \
    _uH.y = (unsigned)_H[2] | ((unsigned)_H[3] << 16);                          \
    _uM.x = (unsigned)_M[0] | ((unsigned)_M[1] << 16);                          \
    _uM.y = (unsigned)_M[2] | ((unsigned)_M[3] << 16);                          \
    *(uint2*)_pl = _uH;                                                         \
    *(uint2*)(_pl + A_PLANE) = _uM;                                             \
    } while (0)

#define CONVERT_A(P0,P1,P2,P3,BUF) do {                                         \
    CONV1(P0, 0, BUF); CONV1(P1, 1, BUF);                                       \
    CONV1(P2, 2, BUF); CONV1(P3, 3, BUF); } while (0)

#define COMPUTE(BUF) do {                                                       \
    const f16x8* _bfp = (const f16x8*)(smem + (BUF) * (BSTAGE_SHORTS * 2));     \
    const unsigned short* _aB = (const unsigned short*)(smem + 65536 + (BUF) * 40960); \
    _Pragma("unroll")                                                           \
    for (int _q = 0; _q < 2; ++_q) {                                            \
        const int _a0 = (wy * 64 + l31) * A_ROW + _q * 16 + lh * 8;             \
        const int _a1 = _a0 + 32 * A_ROW;                                       \
        f16x8 A0h = *(const f16x8*)(_aB + _a0);                                 \
        f16x8 A0m = *(const f16x8*)(_aB + A_PLANE + _a0);                       \
        f16x8 A1h = *(const f16x8*)(_aB + _a1);                                 \
        f16x8 A1m = *(const f16x8*)(_aB + A_PLANE + _a1);                       \
        _Pragma("unroll")                                                       \
        for (int _nt = 0; _nt < 4; ++_nt) {                                     \
            const int _nn = wx * 4 + _nt;                                       \
            f16x8 Bh = _bfp[((_q * 2 + 0) * 8 + _nn) * 64 + lane];              \
            f16x8 Bm = _bfp[((_q * 2 + 1) * 8 + _nn) * 64 + lane];              \
            acc[0][_nt] = __builtin_amdgcn_mfma_f32_32x32x16_f16(A0h, Bh, acc[0][_nt], 0, 0, 0); \
            acc[1][_nt] = __builtin_amdgcn_mfma_f32_32x32x16_f16(A1h, Bh, acc[1][_nt], 0, 0, 0); \
            acc[0][_nt] = __builtin_amdgcn_mfma_f32_32x32x16_f16(A0m, Bh, acc[0][_nt], 0, 0, 0); \
            acc[1][_nt] = __builtin_amdgcn_mfma_f32_32x32x16_f16(A1m, Bh, acc[1][_nt], 0, 0, 0); \
            acc[0][_nt] = __builtin_amdgcn_mfma_f32_32x32x16_f16(A0h, Bm, acc[0][_nt], 0, 0, 0); \
            acc[1][_nt] = __builtin_amdgcn_mfma_f32_32x32x16_f16(A1h, Bm, acc[1][_nt], 0, 0, 0); \
        }                                                                       \
    } } while (0)

    // ---- prolog: stage 0 in buffers 0, prefetch x(1)
    LOAD_PF(aA0, aA1, aA2, aA3, 0);
    GLL_B(0);
    CONVERT_A(aA0, aA1, aA2, aA3, 0);
    LOAD_PF(aA0, aA1, aA2, aA3, 1);
    __syncthreads();

    // ---- main K loop: 2 stages per iteration (register-set alternation)
    for (int s = 0; s < STAGES; s += 2) {
        // even stage s (buffers 0): convert aA -> buf1, load aB <- x(s+2)
        if (s < STAGES - 1) GLL_B(s + 1);
        if (s < STAGES - 2) LOAD_PF(aB0, aB1, aB2, aB3, s + 2);
        COMPUTE(0);
        if (s < STAGES - 1) CONVERT_A(aA0, aA1, aA2, aA3, 1);
        __syncthreads();

        // odd stage s+1 (buffers 1): convert aB -> buf0, load aA <- x(s+3)
        if (s + 1 < STAGES - 1) GLL_B(s + 2);
        if (s + 1 < STAGES - 2) LOAD_PF(aA0, aA1, aA2, aA3, s + 3);
        COMPUTE(1);
        if (s + 1 < STAGES - 1) CONVERT_A(aB0, aB1, aB2, aB3, 0);
        __syncthreads();
    }

    // ---- epilogue (overlays the B-buffer region of smem)
    float* Sp   = (float*)smem;            // [2][256]
    float* sv   = Sp + 2 * NPG;            // [256]
    int*   selr = (int*)(sv + NPG);        // [128]
    float* redT = (float*)(selr + KSEL);   // [256]
    float* redS = redT + NPG;              // [256]

    float bb[4], ww[4];
    #pragma unroll
    for (int nt = 0; nt < 4; ++nt) {
        const int cc = wx * 128 + nt * 32 + l31;
        bb[nt] = b1[cc];
        ww[nt] = W2[cc];
    }
    const float unscale = 1.0f / 65536.0f;   // 2^-(6+10)
    #pragma unroll
    for (int mt = 0; mt < 2; ++mt) {
        float pr[16];
        #pragma unroll
        for (int rr = 0; rr < 16; ++rr) pr[rr] = 0.f;
        #pragma unroll
        for (int nt = 0; nt < 4; ++nt)
            #pragma unroll
            for (int rr = 0; rr < 16; ++rr) {
                float h = fmaf(acc[mt][nt][rr], unscale, bb[nt]);
                h = h > 0.f ? h : 0.f;
                pr[rr] = fmaf(h, ww[nt], pr[rr]);
            }
        #pragma unroll
        for (int mask = 1; mask <= 16; mask <<= 1)
            #pragma unroll
            for (int rr = 0; rr < 16; ++rr)
                pr[rr] += __shfl_xor(pr[rr], mask);
        if (l31 == 0) {
            #pragma unroll
            for (int rr = 0; rr < 16; ++rr) {
                const int row = wy * 64 + mt * 32 + (rr & 3) + 8 * (rr >> 2) + 4 * lh;
                Sp[wx * NPG + row] = pr[rr];
            }
        }
    }
    __syncthreads();

    float sc = 0.f;
    if (tid < NPG) {
        sc = b2[0] + Sp[tid] + Sp[NPG + tid];
        sv[tid] = sc;
    }
    __syncthreads();

    // selection: exact rank (score desc, index asc on ties)
    if (tid < NPG) {
        int rank = 0;
        for (int j = 0; j < NPG; ++j) {
            const float sj = sv[j];
            rank += (sj > sc || (sj == sc && j < tid)) ? 1 : 0;
        }
        const bool sel = rank < KSEL;
        mask_out[g * NPG + tid] = sel ? 1.0f : 0.0f;
        if (sel) selr[rank] = tid;
        redT[tid] = sc;
        redS[tid] = sel ? sc : 0.f;
    }
    __syncthreads();

    for (int off = 128; off > 0; off >>= 1) {
        if (tid < off) { redT[tid] += redT[tid + off]; redS[tid] += redS[tid + off]; }
        __syncthreads();
    }
    if (tid == 0) {
        const float tot = redT[0], ssum = redS[0];
        const float sel_mean = ssum * (1.0f / KSEL);
        const float uns_mean = (tot - ssum) * (1.0f / (NPG - KSEL));
        const float v = 0.5f - (sel_mean - uns_mean);
        loss_per_g[g] = v > 0.f ? v : 0.f;
    }

    // pooled gather; col per thread, 8-way ILP, rows L2/L3-warm
    const int col = tid;
    const float* __restrict__ xg = x + (size_t)g * NPG * FDIM;
    float a0 = 0.f, a1 = 0.f, a2 = 0.f, a3 = 0.f;
    float a4 = 0.f, a5 = 0.f, a6 = 0.f, a7 = 0.f;
    #pragma unroll 2
    for (int n = 0; n < KSEL; n += 8) {
        a0 += xg[(size_t)selr[n + 0] * FDIM + col];
        a1 += xg[(size_t)selr[n + 1] * FDIM + col];
        a2 += xg[(size_t)selr[n + 2] * FDIM + col];
        a3 += xg[(size_t)selr[n + 3] * FDIM + col];
        a4 += xg[(size_t)selr[n + 4] * FDIM + col];
        a5 += xg[(size_t)selr[n + 5] * FDIM + col];
        a6 += xg[(size_t)selr[n + 6] * FDIM + col];
        a7 += xg[(size_t)selr[n + 7] * FDIM + col];
    }
    pooled[g * FDIM + col] = ((a0 + a1) + (a2 + a3)) + ((a4 + a5) + (a6 + a7));

#undef GLL_B
#undef LOAD_PF
#undef CONV1
#undef CONVERT_A
#undef COMPUTE
}

// ---------------------------------------------------------------------------
// K2: topk_loss = sum(loss_per_g) / B * 0.2
// ---------------------------------------------------------------------------
__global__ __launch_bounds__(256)
void loss_kernel(const float* __restrict__ loss_per_g, float* __restrict__ out_loss)
{
    __shared__ float red[256];
    const int t = threadIdx.x;
    red[t] = loss_per_g[t] + loss_per_g[t + 256];
    __syncthreads();
    for (int off = 128; off > 0; off >>= 1) {
        if (t < off) red[t] += red[t + off];
        __syncthreads();
    }
    if (t == 0) out_loss[0] = red[0] * (0.2f / BGRAPHS);
}

extern "C" void kernel_launch(void* const* d_in, const int* in_sizes, int n_in,
                              void* d_out, int out_size, void* d_ws, size_t ws_size,
                              hipStream_t stream)
{
    const float* x  = (const float*)d_in[0];
    const float* W1 = (const float*)d_in[2];
    const float* b1 = (const float*)d_in[3];
    const float* W2 = (const float*)d_in[4];
    const float* b2 = (const float*)d_in[5];

    float* out    = (float*)d_out;
    float* pooled = out;                       // [512*512]
    float* loss   = out + BGRAPHS * FDIM;      // [1]
    float* mask   = loss + 1;                  // [131072]

    float* loss_g       = (float*)d_ws;                               // 2 KB
    unsigned short* wsB = (unsigned short*)((char*)d_ws + 4096);      // 512 KB

    split_w1_kernel<<<128, 256, 0, stream>>>(W1, wsB);
    fused_kernel<<<BGRAPHS, 512, 0, stream>>>(x, wsB, b1, W2, b2,
                                              pooled, mask, loss_g);
    loss_kernel<<<1, 256, 0, stream>>>(loss_g, loss);
}